// Round 8
// baseline (330.589 us; speedup 1.0000x reference)
//
#include <hip/hip_runtime.h>
#include <math.h>

#define T_SEQ 1024
#define C_DIM 1024
#define NB    4
#define NH    16
#define HD    64
#define C3    3072

typedef __attribute__((ext_vector_type(8))) short bf16x8;
typedef __attribute__((ext_vector_type(4))) float f32x4;
typedef unsigned short u16;

union B8 { bf16x8 v; u16 u[8]; unsigned d[4]; };

__device__ inline u16 bf16_rtn(float v) {
    unsigned int u = __float_as_uint(v);
    u += 0x7FFFu + ((u >> 16) & 1u);
    return (u16)(u >> 16);
}
__device__ inline void split_bf16(float v, u16& hi, u16& lo) {
    hi = bf16_rtn(v);
    float hif = __uint_as_float(((unsigned int)hi) << 16);
    lo = bf16_rtn(v - hif);
}

// ---------------------------------------------------------------------------
// LayerNorm fp32 -> split bf16 hi/lo (row stride 1024 both sides).
// ---------------------------------------------------------------------------
__global__ __launch_bounds__(256) void ln_split_kernel(const float* __restrict__ in,
                                                       u16* __restrict__ oh,
                                                       u16* __restrict__ ol,
                                                       const float* __restrict__ g,
                                                       const float* __restrict__ beta) {
    const int row = blockIdx.x;
    const float* x = in + (size_t)row * 1024;
    const int t = threadIdx.x;

    float4 v = *(const float4*)&x[t * 4];
    float s  = v.x + v.y + v.z + v.w;
    float ss = v.x * v.x + v.y * v.y + v.z * v.z + v.w * v.w;
    #pragma unroll
    for (int m = 1; m < 64; m <<= 1) {
        s  += __shfl_xor(s, m);
        ss += __shfl_xor(ss, m);
    }
    __shared__ float red[8];
    const int wave = t >> 6, lane = t & 63;
    if (lane == 0) { red[wave * 2] = s; red[wave * 2 + 1] = ss; }
    __syncthreads();
    s  = red[0] + red[2] + red[4] + red[6];
    ss = red[1] + red[3] + red[5] + red[7];

    const float mu   = s * (1.0f / 1024.0f);
    const float var  = ss * (1.0f / 1024.0f) - mu * mu;
    const float rstd = rsqrtf(var + 1e-5f);

    float4 gg = *(const float4*)&g[t * 4];
    float4 bb = *(const float4*)&beta[t * 4];
    float o[4];
    o[0] = (v.x - mu) * rstd * gg.x + bb.x;
    o[1] = (v.y - mu) * rstd * gg.y + bb.y;
    o[2] = (v.z - mu) * rstd * gg.z + bb.z;
    o[3] = (v.w - mu) * rstd * gg.w + bb.w;

    ushort4 h4, l4;
    split_bf16(o[0], h4.x, l4.x);
    split_bf16(o[1], h4.y, l4.y);
    split_bf16(o[2], h4.z, l4.z);
    split_bf16(o[3], h4.w, l4.w);
    size_t off = (size_t)row * 1024 + t * 4;
    *(ushort4*)&oh[off] = h4;
    *(ushort4*)&ol[off] = l4;
}

// ---------------------------------------------------------------------------
// Fused Q/K LayerNorm. Q: in-place fp32 (stride 3072). K: split bf16 out in
// head-gathered layout Kh/Kl[(b*16+h)*1024 + t][64].
// ---------------------------------------------------------------------------
__global__ __launch_bounds__(256) void ln_qk_kernel(float* __restrict__ qkv,
                                                    const float* __restrict__ qg,
                                                    const float* __restrict__ qb,
                                                    const float* __restrict__ kg,
                                                    const float* __restrict__ kb,
                                                    u16* __restrict__ Kh,
                                                    u16* __restrict__ Kl) {
    const int row = blockIdx.x;
    const int isK = row >> 12;
    const int r = row & 4095;
    float* x = qkv + (size_t)r * C3 + (isK ? 1024 : 0);
    const float* g    = isK ? kg : qg;
    const float* beta = isK ? kb : qb;
    const int t = threadIdx.x;

    float4 v = *(const float4*)&x[t * 4];
    float s  = v.x + v.y + v.z + v.w;
    float ss = v.x * v.x + v.y * v.y + v.z * v.z + v.w * v.w;
    #pragma unroll
    for (int m = 1; m < 64; m <<= 1) {
        s  += __shfl_xor(s, m);
        ss += __shfl_xor(ss, m);
    }
    __shared__ float red[8];
    const int wave = t >> 6, lane = t & 63;
    if (lane == 0) { red[wave * 2] = s; red[wave * 2 + 1] = ss; }
    __syncthreads();
    s  = red[0] + red[2] + red[4] + red[6];
    ss = red[1] + red[3] + red[5] + red[7];

    const float mu   = s * (1.0f / 1024.0f);
    const float var  = ss * (1.0f / 1024.0f) - mu * mu;
    const float rstd = rsqrtf(var + 1e-5f);

    float4 gg = *(const float4*)&g[t * 4];
    float4 bb = *(const float4*)&beta[t * 4];
    float o0 = (v.x - mu) * rstd * gg.x + bb.x;
    float o1 = (v.y - mu) * rstd * gg.y + bb.y;
    float o2 = (v.z - mu) * rstd * gg.z + bb.z;
    float o3 = (v.w - mu) * rstd * gg.w + bb.w;

    if (!isK) {
        float4 o = {o0, o1, o2, o3};
        *(float4*)&x[t * 4] = o;
    } else {
        ushort4 h4, l4;
        split_bf16(o0, h4.x, l4.x);
        split_bf16(o1, h4.y, l4.y);
        split_bf16(o2, h4.z, l4.z);
        split_bf16(o3, h4.w, l4.w);
        const int c = t * 4;
        const int hh = c >> 6, d = c & 63;
        const int b = r >> 10, tt = r & 1023;
        size_t off = ((size_t)((b << 4) + hh) << 16) + (size_t)tt * 64 + d;
        *(ushort4*)&Kh[off] = h4;
        *(ushort4*)&Kl[off] = l4;
    }
}

// ---------------------------------------------------------------------------
// V split + per-head transpose: qkv V region fp32 [t][d] -> Vth/Vtl
// [(b*16+h)*64 + d][1024 t] bf16.
// ---------------------------------------------------------------------------
__global__ __launch_bounds__(256) void vsplit_t(const float* __restrict__ qkv,
                                                u16* __restrict__ Vth,
                                                u16* __restrict__ Vtl) {
    __shared__ float tile[64][68];
    const int bid = blockIdx.x;
    const int tt = bid & 15, h = (bid >> 4) & 15, b = bid >> 8;
    const int t = threadIdx.x;
    const float* src = qkv + (size_t)(b * 1024 + tt * 64) * C3 + 2048 + h * 64;
    #pragma unroll
    for (int i = 0; i < 4; ++i) {
        int idx = i * 256 + t;
        int tr = idx >> 4, dc = (idx & 15) * 4;
        float4 v = *(const float4*)&src[(size_t)tr * C3 + dc];
        tile[tr][dc + 0] = v.x; tile[tr][dc + 1] = v.y;
        tile[tr][dc + 2] = v.z; tile[tr][dc + 3] = v.w;
    }
    __syncthreads();
    #pragma unroll
    for (int i = 0; i < 4; ++i) {
        int idx = i * 256 + t;
        int d = idx >> 4, tc = (idx & 15) * 4;
        ushort4 h4, l4;
        split_bf16(tile[tc + 0][d], h4.x, l4.x);
        split_bf16(tile[tc + 1][d], h4.y, l4.y);
        split_bf16(tile[tc + 2][d], h4.z, l4.z);
        split_bf16(tile[tc + 3][d], h4.w, l4.w);
        size_t off = ((size_t)((b * 16 + h) * 64 + d)) * 1024 + tt * 64 + tc;
        *(ushort4*)&Vth[off] = h4;
        *(ushort4*)&Vtl[off] = l4;
    }
}

// ---------------------------------------------------------------------------
// Weight split + transpose: W[K][N] fp32 -> Th/Tl[N][K] bf16, out row stride
// ldt (u16 units).
// ---------------------------------------------------------------------------
__global__ __launch_bounds__(256) void wsplit_t(const float* __restrict__ W,
                                                u16* __restrict__ Th,
                                                u16* __restrict__ Tl,
                                                int K, int N, int ldt) {
    __shared__ float tile[64][69];
    const int n0 = blockIdx.x * 64, k0 = blockIdx.y * 64;
    const int t = threadIdx.x;
    #pragma unroll
    for (int i = 0; i < 4; ++i) {
        int idx = t + 256 * i;
        int kr = idx >> 4, nc = (idx & 15) * 4;
        float4 v = *(const float4*)&W[(size_t)(k0 + kr) * N + n0 + nc];
        tile[kr][nc + 0] = v.x; tile[kr][nc + 1] = v.y;
        tile[kr][nc + 2] = v.z; tile[kr][nc + 3] = v.w;
    }
    __syncthreads();
    #pragma unroll
    for (int i = 0; i < 4; ++i) {
        int idx = t + 256 * i;
        int nr = idx >> 4, kc = (idx & 15) * 4;
        ushort4 h4, l4;
        split_bf16(tile[kc + 0][nr], h4.x, l4.x);
        split_bf16(tile[kc + 1][nr], h4.y, l4.y);
        split_bf16(tile[kc + 2][nr], h4.z, l4.z);
        split_bf16(tile[kc + 3][nr], h4.w, l4.w);
        size_t o = (size_t)(n0 + nr) * ldt + k0 + kc;
        *(ushort4*)&Th[o] = h4;
        *(ushort4*)&Tl[o] = l4;
    }
}

// ---------------------------------------------------------------------------
// 256x256 4-phase/K-tile interleaved GEMM (T2+T3+T4+T5). K'=3072 via region
// base-select (Ah*Bh | Al*Bh | Ah*Bl). 8 waves (2Mx4N of 128x64), BK=64.
// LDS [mat][buf][ks-half][256 rows][64B] so each staged half is contiguous
// and frees after the phase that consumes it. Per phase: {4-8 ds_read |
// 2 global_load_lds | 16 MFMA (setprio-wrapped) | barrier}. Counted vmcnt(8)
// only at ks boundaries — never 0 in the main loop.
// Pipeline: tile t stages (t+1)ks1 in ph0/ph1 (into other buf) and (t+2)ks0
// in ph2/ph3 (into own buf, whose ks0 was fully consumed by ph1's barrier).
// ---------------------------------------------------------------------------
__global__ __launch_bounds__(512, 1) void gemm256_8ph(
    const u16* __restrict__ Ah, const u16* __restrict__ Al,
    const u16* __restrict__ Bh, const u16* __restrict__ Bl,
    const float* __restrict__ bias, float* __restrict__ C,
    int N, int lda, int ldb) {
    __shared__ __align__(16) u16 SM[65536];  // 128 KB

    const int t    = threadIdx.x;
    const int lane = t & 63;
    const int wid  = t >> 6;
    const int wr   = wid >> 2;      // 0..1 -> rows wr*128
    const int wc   = wid & 3;       // 0..3 -> cols wc*64
    const int m16  = lane & 15, g8 = lane >> 4;

    const int nbx = gridDim.x;
    const int nwg = nbx * gridDim.y;
    int bid = blockIdx.y * nbx + blockIdx.x;
    int swz = (bid & 7) * (nwg >> 3) + (bid >> 3);
    const int bn = (swz % nbx) * 256;
    const int bm = (swz / nbx) * 256;

    f32x4 acc[8][4];
    #pragma unroll
    for (int m = 0; m < 8; ++m)
        #pragma unroll
        for (int n = 0; n < 4; ++n) {
            f32x4 z = {0.0f, 0.0f, 0.0f, 0.0f};
            acc[m][n] = z;
        }

    const int srow = lane >> 2;   // 0..15 row within staged 16-row slab
    const int scol = lane & 3;    // phys 16B chunk within 64B row-half

    // stage one matrix part (part 0=A,1=B) of ks-half of `tile` into buf.
    // 2 wave-instructions; involution swizzle on the global source chunk.
    auto STAGE1 = [&](int tile, int ks, int part, int buf) {
        if (tile > 47) return;
        const int reg = tile >> 4;  // 0: hh, 1: lh, 2: hl
        const u16* src = part == 0 ? ((reg == 1) ? Al : Ah)
                                   : ((reg == 2) ? Bl : Bh);
        const int ld = part == 0 ? lda : ldb;
        const int r0 = part == 0 ? bm : bn;
        const int kloc = ((tile & 15) << 6) + (ks << 5);
        const unsigned mb = (unsigned)(part * 65536 + buf * 32768 + ks * 16384 + wid * 2048);
        #pragma unroll
        for (int j = 0; j < 2; ++j) {
            const int row = wid * 32 + j * 16 + srow;
            const int cl = scol ^ (row & 3);
            const size_t ga = ((size_t)(r0 + row) * ld + kloc + cl * 8) * 2;
            __builtin_amdgcn_global_load_lds(
                (const __attribute__((address_space(1))) void*)((const char*)src + ga),
                (__attribute__((address_space(3))) void*)((char*)SM + mb + j * 1024),
                16, 0, 0);
        }
    };

    // prologue: t0 both halves, t1 ks0
    STAGE1(0, 0, 0, 0); STAGE1(0, 0, 1, 0);
    STAGE1(0, 1, 0, 0); STAGE1(0, 1, 1, 0);
    STAGE1(1, 0, 0, 1); STAGE1(1, 0, 1, 1);
    __builtin_amdgcn_sched_barrier(0);
    asm volatile("s_waitcnt vmcnt(8)" ::: "memory");   // t0 ks0 landed
    __builtin_amdgcn_sched_barrier(0);
    __builtin_amdgcn_s_barrier();
    __builtin_amdgcn_sched_barrier(0);

    for (int tt = 0; tt < 48; ++tt) {
        const int cb = tt & 1;
        const int aB = cb * 16384;            // u16 base: A[buf]
        const int bB = 32768 + cb * 16384;    // u16 base: B[buf]
        bf16x8 bfr[4], afr[4];

        // ===== phase 0: ks0, B + A-mh0, 16 MFMA =====
        #pragma unroll
        for (int n = 0; n < 4; ++n) {
            const int r = wc * 64 + n * 16 + m16;
            bfr[n] = *(const bf16x8*)&SM[bB + r * 32 + ((g8 ^ (r & 3)) << 3)];
        }
        #pragma unroll
        for (int m = 0; m < 4; ++m) {
            const int r = wr * 128 + m * 16 + m16;
            afr[m] = *(const bf16x8*)&SM[aB + r * 32 + ((g8 ^ (r & 3)) << 3)];
        }
        STAGE1(tt + 1, 1, 0, cb ^ 1);
        __builtin_amdgcn_s_setprio(1);
        #pragma unroll
        for (int m = 0; m < 4; ++m)
            #pragma unroll
            for (int n = 0; n < 4; ++n)
                acc[m][n] = __builtin_amdgcn_mfma_f32_16x16x32_bf16(afr[m], bfr[n], acc[m][n], 0, 0, 0);
        __builtin_amdgcn_s_setprio(0);
        __builtin_amdgcn_sched_barrier(0);
        __builtin_amdgcn_s_barrier();
        __builtin_amdgcn_sched_barrier(0);

        // ===== phase 1: ks0, A-mh1 (B kept in regs), 16 MFMA =====
        #pragma unroll
        for (int m = 0; m < 4; ++m) {
            const int r = wr * 128 + (m + 4) * 16 + m16;
            afr[m] = *(const bf16x8*)&SM[aB + r * 32 + ((g8 ^ (r & 3)) << 3)];
        }
        STAGE1(tt + 1, 1, 1, cb ^ 1);
        __builtin_amdgcn_s_setprio(1);
        #pragma unroll
        for (int m = 0; m < 4; ++m)
            #pragma unroll
            for (int n = 0; n < 4; ++n)
                acc[m + 4][n] = __builtin_amdgcn_mfma_f32_16x16x32_bf16(afr[m], bfr[n], acc[m + 4][n], 0, 0, 0);
        __builtin_amdgcn_s_setprio(0);
        __builtin_amdgcn_sched_barrier(0);
        if (tt < 47) {
            asm volatile("s_waitcnt vmcnt(8)" ::: "memory");   // this tile's ks1 landed
        } else {
            asm volatile("s_waitcnt vmcnt(0)" ::: "memory");
        }
        __builtin_amdgcn_sched_barrier(0);
        __builtin_amdgcn_s_barrier();
        __builtin_amdgcn_sched_barrier(0);

        // ===== phase 2: ks1, B + A-mh0, 16 MFMA =====
        #pragma unroll
        for (int n = 0; n < 4; ++n) {
            const int r = wc * 64 + n * 16 + m16;
            bfr[n] = *(const bf16x8*)&SM[bB + 8192 + r * 32 + ((g8 ^ (r & 3)) << 3)];
        }
        #pragma unroll
        for (int m = 0; m < 4; ++m) {
            const int r = wr * 128 + m * 16 + m16;
            afr[m] = *(const bf16x8*)&SM[aB + 8192 + r * 32 + ((g8 ^ (r & 3)) << 3)];
        }
        STAGE1(tt + 2, 0, 0, cb);
        __builtin_amdgcn_s_setprio(1);
        #pragma unroll
        for (int m = 0; m < 4; ++m)
            #pragma unroll
            for (int n = 0; n < 4; ++n)
                acc[m][n] = __builtin_amdgcn_mfma_f32_16x16x32_bf16(afr[m], bfr[n], acc[m][n], 0, 0, 0);
        __builtin_amdgcn_s_setprio(0);
        __builtin_amdgcn_sched_barrier(0);
        __builtin_amdgcn_s_barrier();
        __builtin_amdgcn_sched_barrier(0);

        // ===== phase 3: ks1, A-mh1, 16 MFMA =====
        #pragma unroll
        for (int m = 0; m < 4; ++m) {
            const int r = wr * 128 + (m + 4) * 16 + m16;
            afr[m] = *(const bf16x8*)&SM[aB + 8192 + r * 32 + ((g8 ^ (r & 3)) << 3)];
        }
        STAGE1(tt + 2, 0, 1, cb);
        __builtin_amdgcn_s_setprio(1);
        #pragma unroll
        for (int m = 0; m < 4; ++m)
            #pragma unroll
            for (int n = 0; n < 4; ++n)
                acc[m + 4][n] = __builtin_amdgcn_mfma_f32_16x16x32_bf16(afr[m], bfr[n], acc[m + 4][n], 0, 0, 0);
        __builtin_amdgcn_s_setprio(0);
        __builtin_amdgcn_sched_barrier(0);
        if (tt < 46) {
            asm volatile("s_waitcnt vmcnt(8)" ::: "memory");   // next tile's ks0 landed
        } else if (tt == 46) {
            asm volatile("s_waitcnt vmcnt(4)" ::: "memory");   // no (t+2) stages issued
        }
        __builtin_amdgcn_sched_barrier(0);
        __builtin_amdgcn_s_barrier();
        __builtin_amdgcn_sched_barrier(0);
    }

    #pragma unroll
    for (int m = 0; m < 8; ++m) {
        const int row0 = bm + wr * 128 + m * 16 + (g8 << 2);
        #pragma unroll
        for (int n = 0; n < 4; ++n) {
            const int col = bn + wc * 64 + n * 16 + m16;
            const float bv = bias[col];
            #pragma unroll
            for (int e = 0; e < 4; ++e)
                C[(size_t)(row0 + e) * N + col] = acc[m][n][e] + bv;
        }
    }
}

// ---------------------------------------------------------------------------
// 128x128 split GEMM (kept for proj: grid 32x8 = 256 blocks = full CU cover).
// ---------------------------------------------------------------------------
__global__ __launch_bounds__(256) void gemm_mfma_split(
    const u16* __restrict__ Ah, const u16* __restrict__ Al,
    const u16* __restrict__ Bh, const u16* __restrict__ Bl,
    const float* __restrict__ bias, float* __restrict__ C,
    int M, int N, int K, int lda, int ldb) {
    __shared__ u16 sAh[128 * 32], sAl[128 * 32], sBh[128 * 32], sBl[128 * 32];

    const int t    = threadIdx.x;
    const int lane = t & 63;
    const int wid  = t >> 6;
    const int wr   = wid >> 1, wc = wid & 1;

    const int nbx = gridDim.x;
    const int nwg = nbx * gridDim.y;
    int bid = blockIdx.y * nbx + blockIdx.x;
    int swz = (bid & 7) * (nwg >> 3) + (bid >> 3);
    const int bn = (swz % nbx) * 128;
    const int bm = (swz / nbx) * 128;

    const int jr    = lane >> 2;
    const int cphys = lane & 3;
    const int m16 = lane & 15, g8 = lane >> 4;

    f32x4 acc[4][4];
    #pragma unroll
    for (int m = 0; m < 4; ++m)
        #pragma unroll
        for (int n = 0; n < 4; ++n) {
            f32x4 z = {0.0f, 0.0f, 0.0f, 0.0f};
            acc[m][n] = z;
        }

    for (int k0 = 0; k0 < K; k0 += 32) {
        __syncthreads();
        #pragma unroll
        for (int jj = 0; jj < 2; ++jj) {
            const int j = wid * 2 + jj;
            const int r = (j << 4) + jr;
            const int cl = cphys ^ (r & 3);
            const size_t ga = ((size_t)(bm + r) * lda + k0 + (cl << 3)) * 2;
            const size_t gb = ((size_t)(bn + r) * ldb + k0 + (cl << 3)) * 2;
            const unsigned ldso = (unsigned)(j << 10);
            __builtin_amdgcn_global_load_lds(
                (const __attribute__((address_space(1))) void*)((const char*)Ah + ga),
                (__attribute__((address_space(3))) void*)((char*)sAh + ldso), 16, 0, 0);
            __builtin_amdgcn_global_load_lds(
                (const __attribute__((address_space(1))) void*)((const char*)Al + ga),
                (__attribute__((address_space(3))) void*)((char*)sAl + ldso), 16, 0, 0);
            __builtin_amdgcn_global_load_lds(
                (const __attribute__((address_space(1))) void*)((const char*)Bh + gb),
                (__attribute__((address_space(3))) void*)((char*)sBh + ldso), 16, 0, 0);
            __builtin_amdgcn_global_load_lds(
                (const __attribute__((address_space(1))) void*)((const char*)Bl + gb),
                (__attribute__((address_space(3))) void*)((char*)sBl + ldso), 16, 0, 0);
        }
        __syncthreads();

        bf16x8 ah[4], al[4], bh[4], bl[4];
        #pragma unroll
        for (int m = 0; m < 4; ++m) {
            const int r = wr * 64 + m * 16 + m16;
            const int off = (r << 5) + ((g8 ^ (m16 & 3)) << 3);
            ah[m] = *(const bf16x8*)&sAh[off];
            al[m] = *(const bf16x8*)&sAl[off];
        }
        #pragma unroll
        for (int n = 0; n < 4; ++n) {
            const int r = wc * 64 + n * 16 + m16;
            const int off = (r << 5) + ((g8 ^ (m16 & 3)) << 3);
            bh[n] = *(const bf16x8*)&sBh[off];
            bl[n] = *(const bf16x8*)&sBl[off];
        }
        #pragma unroll
        for (int m = 0; m < 4; ++m)
            #pragma unroll
            for (int n = 0; n < 4; ++n) {
                acc[m][n] = __builtin_amdgcn_mfma_f32_16x16x32_bf16(ah[m], bh[n], acc[m][n], 0, 0, 0);
                acc[m][n] = __builtin_amdgcn_mfma_f32_16x16x32_bf16(al[m], bh[n], acc[m][n], 0, 0, 0);
                acc[m][n] = __builtin_amdgcn_mfma_f32_16x16x32_bf16(ah[m], bl[n], acc[m][n], 0, 0, 0);
            }
    }

    #pragma unroll
    for (int m = 0; m < 4; ++m) {
        const int row0 = bm + wr * 64 + m * 16 + (g8 << 2);
        #pragma unroll
        for (int n = 0; n < 4; ++n) {
            const int col = bn + wc * 64 + n * 16 + m16;
            const float bv = bias[col];
            #pragma unroll
            for (int e = 0; e < 4; ++e)
                C[(size_t)(row0 + e) * N + col] = acc[m][n][e] + bv;
        }
    }
}

// ---------------------------------------------------------------------------
// MFMA flash attention (unchanged — kept stable so its counters surface for
// diagnosis next round).
// ---------------------------------------------------------------------------
__global__ __launch_bounds__(256) void attn_mfma(const float* __restrict__ qkv,
                                                 const u16* __restrict__ Kh,
                                                 const u16* __restrict__ Kl,
                                                 const u16* __restrict__ Vth,
                                                 const u16* __restrict__ Vtl,
                                                 u16* __restrict__ att) {
    __shared__ __align__(16) u16 SM[32768];  // 64 KB

    const int t    = threadIdx.x;
    const int lane = t & 63;
    const int wv   = t >> 6;
    const int m16  = lane & 15, g8 = lane >> 4;

    const int bid  = blockIdx.x;
    const int work = (bid & 7) * 128 + (bid >> 3);
    const int qt = work & 15;
    const int bh = work >> 4;
    const int h  = bh & 15;
    const int b  = bh >> 4;
    const int q0 = qt * 64;

    const int srow = lane >> 3;
    const int scl  = (lane & 7) ^ srow;
    const size_t kvrow0 = (size_t)bh << 16;

    auto stageK = [&](int kt) {
        const int kb = kt * 64;
        #pragma unroll
        for (int issue = 0; issue < 2; ++issue) {
            const int rloc = (issue * 4 + wv) * 8 + srow;
            const size_t go = (kvrow0 + (size_t)(kb + rloc) * 64 + scl * 8) * 2;
            const unsigned lo = (unsigned)((issue * 4 + wv) * 1024);
            __builtin_amdgcn_global_load_lds(
                (const __attribute__((address_space(1))) void*)((const char*)Kh + go),
                (__attribute__((address_space(3))) void*)((char*)SM + lo), 16, 0, 0);
            __builtin_amdgcn_global_load_lds(
                (const __attribute__((address_space(1))) void*)((const char*)Kl + go),
                (__attribute__((address_space(3))) void*)((char*)SM + 8192 + lo), 16, 0, 0);
        }
    };
    auto stageV = [&](int kt, int bsel) {
        const int kb = kt * 64;
        #pragma unroll
        for (int issue = 0; issue < 2; ++issue) {
            const int rloc = (issue * 4 + wv) * 8 + srow;
            const size_t go = (kvrow0 + (size_t)rloc * 1024 + kb + scl * 8) * 2;
            const unsigned lo = (unsigned)(16384 + bsel * 16384 + (issue * 4 + wv) * 1024);
            __builtin_amdgcn_global_load_lds(
                (const __attribute__((address_space(1))) void*)((const char*)Vth + go),
                (__attribute__((address_space(3))) void*)((char*)SM + lo), 16, 0, 0);
            __builtin_amdgcn_global_load_lds(
                (const __attribute__((address_space(1))) void*)((const char*)Vtl + go),
                (__attribute__((address_space(3))) void*)((char*)SM + 8192 + lo), 16, 0, 0);
        }
    };

    bf16x8 qh[2], ql[2];
    {
        const float* qrow = qkv + (size_t)(b * T_SEQ + q0 + wv * 16 + m16) * C3 + h * HD;
        #pragma unroll
        for (int ds = 0; ds < 2; ++ds) {
            float4 a = *(const float4*)&qrow[ds * 32 + g8 * 8];
            float4 c = *(const float4*)&qrow[ds * 32 + g8 * 8 + 4];
            float q8[8] = {a.x, a.y, a.z, a.w, c.x, c.y, c.z, c.w};
            B8 hh, ll;
            #pragma unroll
            for (int j = 0; j < 8; ++j) {
                u16 hi, lo;
                split_bf16(q8[j] * 0.125f, hi, lo);
                hh.u[j] = hi; ll.u[j] = lo;
            }
            qh[ds] = hh.v; ql[ds] = ll.v;
        }
    }

    f32x4 acc_o[4];
    #pragma unroll
    for (int i = 0; i < 4; ++i) { f32x4 z = {0, 0, 0, 0}; acc_o[i] = z; }
    float m_run = -INFINITY, l_run = 0.0f;

    u16* Phw = SM + 24576 + wv * 1024;
    u16* Plw = SM + 28672 + wv * 1024;

    stageK(0);
    stageV(0, 0);
    asm volatile("s_waitcnt vmcnt(0)" ::: "memory");
    __builtin_amdgcn_s_barrier();
    __builtin_amdgcn_sched_barrier(0);

    int vsel = 0;
    for (int kt = 0; kt < 16; ++kt) {
        f32x4 accs[4];
        #pragma unroll
        for (int i = 0; i < 4; ++i) { f32x4 z = {0, 0, 0, 0}; accs[i] = z; }
        #pragma unroll
        for (int ds = 0; ds < 2; ++ds) {
            #pragma unroll
            for (int sub = 0; sub < 4; ++sub) {
                const int row = sub * 16 + m16;
                const int idx = row * 64 + ((((ds * 4 + g8)) ^ (m16 & 7)) << 3);
                bf16x8 kh = *(const bf16x8*)&SM[idx];
                bf16x8 kl = *(const bf16x8*)&SM[4096 + idx];
                accs[sub] = __builtin_amdgcn_mfma_f32_16x16x32_bf16(kh, qh[ds], accs[sub], 0, 0, 0);
                accs[sub] = __builtin_amdgcn_mfma_f32_16x16x32_bf16(kl, qh[ds], accs[sub], 0, 0, 0);
                accs[sub] = __builtin_amdgcn_mfma_f32_16x16x32_bf16(kh, ql[ds], accs[sub], 0, 0, 0);
            }
        }

        __builtin_amdgcn_sched_barrier(0);
        __builtin_amdgcn_s_barrier();
        __builtin_amdgcn_sched_barrier(0);
        if (kt < 15) { stageK(kt + 1); stageV(kt + 1, vsel ^ 1); }

        float mt = accs[0][0];
        #pragma unroll
        for (int sub = 0; sub < 4; ++sub)
            #pragma unroll
            for (int e = 0; e < 4; ++e) mt = fmaxf(mt, accs[sub][e]);
        mt = fmaxf(mt, __shfl_xor(mt, 16));
        mt = fmaxf(mt, __shfl_xor(mt, 32));
        const float mnew = fmaxf(m_run, mt);
        const float fsc = __expf(m_run - mnew);
        float p[4][4];
        float ts = 0.0f;
        #pragma unroll
        for (int sub = 0; sub < 4; ++sub)
            #pragma unroll
            for (int e = 0; e < 4; ++e) {
                p[sub][e] = __expf(accs[sub][e] - mnew);
                ts += p[sub][e];
            }
        ts += __shfl_xor(ts, 16);
        ts += __shfl_xor(ts, 32);
        l_run = l_run * fsc + ts;
        m_run = mnew;
        #pragma unroll
        for (int d = 0; d < 4; ++d)
            #pragma unroll
            for (int e = 0; e < 4; ++e) acc_o[d][e] *= fsc;

        #pragma unroll
        for (int sub = 0; sub < 4; ++sub)
            #pragma unroll
            for (int pp = 0; pp < 2; ++pp) {
                float p0 = p[sub][2 * pp], p1 = p[sub][2 * pp + 1];
                u16 h0, l0, h1, l1;
                split_bf16(p0, h0, l0);
                split_bf16(p1, h1, l1);
                unsigned hw = (unsigned)h0 | ((unsigned)h1 << 16);
                unsigned lw = (unsigned)l0 | ((unsigned)l1 << 16);
                const int idx = m16 * 64 + (((2 * sub + (g8 >> 1)) ^ (m16 & 7)) << 3)
                                + 4 * (g8 & 1) + 2 * pp;
                *(unsigned*)&Phw[idx] = hw;
                *(unsigned*)&Plw[idx] = lw;
            }

        bf16x8 pfh[2], pfl[2];
        #pragma unroll
        for (int ks = 0; ks < 2; ++ks) {
            const int idx = m16 * 64 + ((((ks * 4 + g8)) ^ (m16 & 7)) << 3);
            pfh[ks] = *(const bf16x8*)&Phw[idx];
            pfl[ks] = *(const bf16x8*)&Plw[idx];
        }

        const int vb = 8192 + vsel * 8192;
        #pragma unroll
        for (int dsub = 0; dsub < 4; ++dsub) {
            #pragma unroll
            for (int ks = 0; ks < 2; ++ks) {
                const int vrow = dsub * 16 + m16;
                const int vidx = vb + vrow * 64 + ((((ks * 4 + g8)) ^ (m16 & 7)) << 3);
                bf16x8 vh = *(const bf16x8*)&SM[vidx];
                bf16x8 vl = *(const bf16x8*)&SM[4096 + vidx];
                acc_o[dsub] = __builtin_amdgcn_mfma_f32_16x16x32_bf16(vh, pfh[ks], acc_o[dsub], 0, 0, 0);
                acc_o[dsub] = __builtin_amdgcn_mfma_f32_16x16x32_bf16(vh, pfl[ks], acc_o[dsub], 0, 0, 0);
                acc_o[dsub] = __builtin_amdgcn_mfma_f32_16x16x32_bf16(vl, pfh[ks], acc_o[dsub], 0, 0, 0);
            }
        }

        __builtin_amdgcn_sched_barrier(0);
        asm volatile("s_waitcnt vmcnt(0)" ::: "memory");
        __builtin_amdgcn_s_barrier();
        __builtin_amdgcn_sched_barrier(0);
        vsel ^= 1;
    }

    const float linv = 1.0f / l_run;
    #pragma unroll
    for (int dsub = 0; dsub < 4; ++dsub)
        #pragma unroll
        for (int pp = 0; pp < 2; ++pp) {
            float o0 = acc_o[dsub][2 * pp] * linv;
            float o1 = acc_o[dsub][2 * pp + 1] * linv;
            u16 h0, l0, h1, l1;
            split_bf16(o0, h0, l0);
            split_bf16(o1, h1, l1);
            unsigned hw = (unsigned)h0 | ((unsigned)h1 << 16);
            unsigned lw = (unsigned)l0 | ((unsigned)l1 << 16);
            const int idx = m16 * 64 + (((2 * dsub + (g8 >> 1)) ^ (m16 & 7)) << 3)
                            + 4 * (g8 & 1) + 2 * pp;
            *(unsigned*)&Phw[idx] = hw;
            *(unsigned*)&Plw[idx] = lw;
        }
    __syncthreads();
    #pragma unroll
    for (int i = 0; i < 2; ++i) {
        int s = t + 256 * i;
        int q_l = s >> 3, dg8 = s & 7;
        const int idx = q_l * 64 + ((dg8 ^ (q_l & 7)) << 3);
        bf16x8 oh = *(const bf16x8*)&SM[24576 + idx];
        bf16x8 ol = *(const bf16x8*)&SM[28672 + idx];
        size_t off = (size_t)(b * T_SEQ + q0 + q_l) * 6144 + 2048 + h * HD + dg8 * 8;
        *(bf16x8*)&att[off] = oh;
        *(bf16x8*)&att[off + 1024] = ol;
    }
}

// ---------------------------------------------------------------------------
extern "C" void kernel_launch(void* const* d_in, const int* in_sizes, int n_in,
                              void* d_out, int out_size, void* d_ws, size_t ws_size,
                              hipStream_t stream) {
    const float* x      = (const float*)d_in[0];
    const float* norm_g = (const float*)d_in[1];
    const float* norm_b = (const float*)d_in[2];
    const float* qkv_w  = (const float*)d_in[3];
    const float* qkv_b  = (const float*)d_in[4];
    const float* qln_g  = (const float*)d_in[5];
    const float* qln_b  = (const float*)d_in[6];
    const float* kln_g  = (const float*)d_in[7];
    const float* kln_b  = (const float*)d_in[8];
    const float* proj_w = (const float*)d_in[9];
    const float* proj_b = (const float*)d_in[10];
    float* out = (float*)d_out;

    char* w = (char*)d_ws;
    float* qkv    = (float*)w;
    u16* qkv_u16  = (u16*)w;
    u16* xn_hi    = (u16*)(w + 50331648);
    u16* xn_lo    = (u16*)(w + 58720256);
    u16* wq_hi    = (u16*)(w + 67108864);
    u16* wq_lo    = (u16*)(w + 73400320);
    u16* Kh       = xn_hi;
    u16* Kl       = xn_lo;
    u16* Vth      = (u16*)(w + 67108864);
    u16* Vtl      = (u16*)(w + 75497472);
    u16* pw_hi    = qkv_u16 + 4096;  // overlay qkv V-region, stride 6144
    u16* pw_lo    = qkv_u16 + 5120;
    u16* att_hi   = qkv_u16 + 2048;  // overlay qkv K-region, stride 6144
    u16* att_lo   = qkv_u16 + 3072;

    const int rows = NB * T_SEQ;  // 4096

    ln_split_kernel<<<rows, 256, 0, stream>>>(x, xn_hi, xn_lo, norm_g, norm_b);
    wsplit_t<<<dim3(C3 / 64, C_DIM / 64), 256, 0, stream>>>(qkv_w, wq_hi, wq_lo, C_DIM, C3, 1024);
    gemm256_8ph<<<dim3(C3 / 256, rows / 256), 512, 0, stream>>>(
        xn_hi, xn_lo, wq_hi, wq_lo, qkv_b, qkv, C3, 1024, 1024);
    ln_qk_kernel<<<2 * rows, 256, 0, stream>>>(qkv, qln_g, qln_b, kln_g, kln_b, Kh, Kl);
    vsplit_t<<<1024, 256, 0, stream>>>(qkv, Vth, Vtl);
    wsplit_t<<<dim3(C_DIM / 64, C_DIM / 64), 256, 0, stream>>>(proj_w, pw_hi, pw_lo, C_DIM, C_DIM, 6144);
    attn_mfma<<<1024, 256, 0, stream>>>(qkv, Kh, Kl, Vth, Vtl, qkv_u16);
    gemm_mfma_split<<<dim3(C_DIM / 128, rows / 128), 256, 0, stream>>>(
        att_hi, att_lo, pw_hi, pw_lo, proj_b, out, rows, C_DIM, C_DIM, 6144, 6144);
}